// Round 7
// baseline (451.644 us; speedup 1.0000x reference)
//
#include <hip/hip_runtime.h>
#include <hip/hip_bf16.h>

#define NN 50000
#define NE 1600000
#define FF 128
#define CC 16
#define NB ((NN + 63) / 64)       // 782 dst-buckets of 64 nodes
#define NBLK 128                  // partition blocks for the sort
#define CH ((NE + NBLK - 1) / NBLK)   // 12500 edges per partition block

using bf16 = __hip_bfloat16;

// Runtime-dtype load: isbf selects bf16 vs f32 interpretation of p.
static __device__ __forceinline__ float ldf(const void* p, int i, int isbf){
    return isbf ? __bfloat162float(((const bf16*)p)[i]) : ((const float*)p)[i];
}
// Unpack a uint holding two bf16 (features 2k, 2k+1).
static __device__ __forceinline__ float bflo(unsigned u){
    union{unsigned x; float f;} c; c.x = u << 16; return c.f;
}
static __device__ __forceinline__ float bfhi(unsigned u){
    union{unsigned x; float f;} c; c.x = u & 0xFFFF0000u; return c.f;
}
static __device__ __forceinline__ float rdlanef(float v, int l){
    return __int_as_float(__builtin_amdgcn_readlane(__float_as_int(v), l));
}

// ---------------- dtype detector ----------------
__global__ __launch_bounds__(256) void k_detect(const unsigned short* __restrict__ u,
                                                int* __restrict__ flag){
    int t = threadIdx.x;
    unsigned short lo = u[2 * t];
    int e = (lo >> 7) & 0xFF;
    int sane = (e >= 117 && e <= 137) ? 1 : 0;
    __shared__ int cnt;
    if (t == 0) cnt = 0;
    __syncthreads();
    atomicAdd(&cnt, sane);
    __syncthreads();
    if (t == 0) *flag = (cnt >= 128) ? 1 : 0;   // 1 => bf16 data
}

__global__ __launch_bounds__(256) void k_zero(int* __restrict__ p, int n){
    int i = blockIdx.x * 256 + threadIdx.x;
    if (i < n) p[i] = 0;
}

// ---------------- CSR build: hierarchical counting sort by dst ----------------

__global__ __launch_bounds__(256) void k_bcount(const int* __restrict__ dst, int* __restrict__ bcounts,
                                                int* __restrict__ bh){
    __shared__ int hist[NB];
    const int t = threadIdx.x, b = blockIdx.x;
    for (int i = t; i < NB; i += 256) hist[i] = 0;
    __syncthreads();
    const int beg = b * CH, end = (beg + CH < NE) ? beg + CH : NE;
    for (int i = beg + t; i < end; i += 256){
        int d = dst[i];
        if ((unsigned)d >= NN) d = 0;
        atomicAdd(&hist[d >> 6], 1);
    }
    __syncthreads();
    for (int k = t; k < NB; k += 256){
        int v = hist[k];
        bh[k * NBLK + b] = v;
        if (v) atomicAdd(&bcounts[k], v);
    }
}

__global__ __launch_bounds__(256) void k_bscan(const int* __restrict__ bcounts, int* __restrict__ bbase,
                                               int* __restrict__ rowptr){
    __shared__ int s[256];
    const int t = threadIdx.x;
    constexpr int PT = (NB + 255) / 256;   // 4
    int loc[PT];
    int sum = 0;
    #pragma unroll
    for (int i = 0; i < PT; i++){
        int idx = t * PT + i;
        int v = (idx < NB) ? bcounts[idx] : 0;
        loc[i] = sum;
        sum += v;
    }
    s[t] = sum; __syncthreads();
    for (int off = 1; off < 256; off <<= 1){
        int x = (t >= off) ? s[t - off] : 0;
        __syncthreads();
        s[t] += x;
        __syncthreads();
    }
    int base = (t > 0) ? s[t - 1] : 0;
    #pragma unroll
    for (int i = 0; i < PT; i++){
        int idx = t * PT + i;
        if (idx < NB) bbase[idx] = base + loc[i];
    }
    if (t == 255){
        bbase[NB] = s[255];      // == NE
        rowptr[NN] = s[255];
    }
}

// Per-bucket offsets: wave-per-bucket shfl scan over the 128 per-block counts.
__global__ __launch_bounds__(256) void k_boffset(const int* __restrict__ bbase, int* __restrict__ bh){
    int k = blockIdx.x * 4 + (threadIdx.x >> 6);
    int lane = threadIdx.x & 63;
    if (k >= NB) return;
    int v0 = bh[k * NBLK + 2 * lane];
    int v1 = bh[k * NBLK + 2 * lane + 1];
    int s = v0 + v1;
    #pragma unroll
    for (int off = 1; off < 64; off <<= 1){
        int x = __shfl_up(s, off);
        if (lane >= off) s += x;
    }
    int base = bbase[k] + s - (v0 + v1);   // exclusive prefix of pair sums
    bh[k * NBLK + 2 * lane]     = base;
    bh[k * NBLK + 2 * lane + 1] = base + v0;
}

__global__ __launch_bounds__(256) void k_bucket(const int* __restrict__ src, const int* __restrict__ dst,
                                                const int* __restrict__ bh, unsigned* __restrict__ bpairs){
    __shared__ int cur[NB];
    const int t = threadIdx.x, b = blockIdx.x;
    for (int k = t; k < NB; k += 256) cur[k] = bh[k * NBLK + b];
    __syncthreads();
    const int beg = b * CH, end = (beg + CH < NE) ? beg + CH : NE;
    for (int i = beg + t; i < end; i += 256){
        int s = src[i];
        int d = dst[i];
        if ((unsigned)s >= NN) s = 0;
        if ((unsigned)d >= NN) d = 0;
        int p = atomicAdd(&cur[d >> 6], 1);
        if ((unsigned)p < NE) bpairs[p] = (unsigned)s | ((unsigned)(d & 63) << 16);
    }
}

__global__ __launch_bounds__(256) void k_bsort(const unsigned* __restrict__ bpairs, const int* __restrict__ bbase,
                                               int* __restrict__ rowptr, int* __restrict__ csrsrc){
    __shared__ int cnt[64];
    __shared__ int cur[64];
    const int t = threadIdx.x;
    const int b = blockIdx.x;
    const int base = bbase[b];
    const int endb = bbase[b + 1];
    if (t < 64) cnt[t] = 0;
    __syncthreads();
    for (int i = base + t; i < endb; i += 256)
        atomicAdd(&cnt[bpairs[i] >> 16], 1);
    __syncthreads();
    if (t < 64){   // wave 0 exactly: 64-lane exclusive scan via shfl
        int v = cnt[t];
        int inc = v;
        #pragma unroll
        for (int off = 1; off < 64; off <<= 1){
            int x = __shfl_up(inc, off);
            if (t >= off) inc += x;
        }
        int excl = inc - v;
        cur[t] = excl;
        int d = b * 64 + t;
        if (d < NN) rowptr[d] = base + excl;
    }
    __syncthreads();
    for (int i = base + t; i < endb; i += 256){
        unsigned pr = bpairs[i];
        int p = atomicAdd(&cur[pr >> 16], 1);
        csrsrc[base + p] = (int)(pr & 0xFFFFu);
    }
}

// ---------------- GEMM: ft = X @ W  (X: [NN,FF], W: [FF,OUT] row-major) ----------------
// FTBF: store ft as bf16 (ushort) instead of f32.

template<bool XDYN, int OUT, int NPT, bool FTBF>
__global__ __launch_bounds__(256) void k_gemm(const void* __restrict__ X, const void* __restrict__ W,
                                              const int* __restrict__ dflag, void* __restrict__ ft){
    constexpr int BN = 256 * NPT / OUT;   // 16 for both instantiations
    __shared__ float xs[FF][BN + 1];      // transposed, +1 pad kills store conflicts
    const int isbf = *dflag;
    const int t  = threadIdx.x;
    const int n0 = blockIdx.x * BN;

    for (int idx = t; idx < BN * FF; idx += 256){
        int r = idx >> 7;        // node within tile
        int c = idx & 127;       // feature
        int n = n0 + r;
        float v = 0.f;
        if (n < NN){
            if (XDYN) v = ldf(X, n * FF + c, isbf);
            else      v = ((const float*)X)[n * FF + c];
        }
        xs[c][r] = v;
    }
    __syncthreads();

    const int tx = t % OUT;
    const int rg = t / OUT;      // row group
    float acc[NPT];
    #pragma unroll
    for (int i = 0; i < NPT; i++) acc[i] = 0.f;

    if (isbf){
        const bf16* Wb = (const bf16*)W;
        for (int k = 0; k < FF; k++){
            float w = __bfloat162float(Wb[k * OUT + tx]);
            #pragma unroll
            for (int i = 0; i < NPT; i++) acc[i] += w * xs[k][rg * NPT + i];
        }
    } else {
        const float* Wf = (const float*)W;
        for (int k = 0; k < FF; k++){
            float w = Wf[k * OUT + tx];
            #pragma unroll
            for (int i = 0; i < NPT; i++) acc[i] += w * xs[k][rg * NPT + i];
        }
    }

    #pragma unroll
    for (int i = 0; i < NPT; i++){
        int n = n0 + rg * NPT + i;
        if (n < NN){
            if (FTBF) ((bf16*)ft)[n * OUT + tx] = __float2bfloat16(acc[i]);
            else      ((float*)ft)[n * OUT + tx] = acc[i];
        }
    }
}

// ---------------- el/er: per-node dot with attention vectors ----------------

template<int OUT, bool FTBF>
__global__ __launch_bounds__(256) void k_el_er(const void* __restrict__ ft, const void* __restrict__ al,
                                               const void* __restrict__ ar, const int* __restrict__ dflag,
                                               float* __restrict__ el, float* __restrict__ er){
    const int isbf = *dflag;
    int lane = threadIdx.x & 63;
    int n = blockIdx.x * 4 + (threadIdx.x >> 6);
    if (n >= NN) return;
    float pl = 0.f, pr = 0.f;
    if (OUT == 128){
        if (FTBF){
            unsigned u = ((const unsigned*)ft)[n * 64 + lane];   // features 2*lane, 2*lane+1
            float v0 = bflo(u), v1 = bfhi(u);
            pl = v0 * ldf(al, 2 * lane, isbf) + v1 * ldf(al, 2 * lane + 1, isbf);
            pr = v0 * ldf(ar, 2 * lane, isbf) + v1 * ldf(ar, 2 * lane + 1, isbf);
        } else {
            float v0 = ((const float*)ft)[n * 128 + lane];
            float v1 = ((const float*)ft)[n * 128 + 64 + lane];
            pl = v0 * ldf(al, lane, isbf) + v1 * ldf(al, 64 + lane, isbf);
            pr = v0 * ldf(ar, lane, isbf) + v1 * ldf(ar, 64 + lane, isbf);
        }
    } else {
        if (lane < OUT){
            float v = ((const float*)ft)[n * OUT + lane];
            pl = v * ldf(al, lane, isbf);
            pr = v * ldf(ar, lane, isbf);
        }
    }
    #pragma unroll
    for (int off = 32; off; off >>= 1){
        pl += __shfl_xor(pl, off);
        pr += __shfl_xor(pr, off);
    }
    if (lane == 0){ el[n] = pl; er[n] = pr; }
}

// ---------------- Aggregation: one wave per dst node, edge softmax + weighted sum ----------------
// Pass 1 computes logits, max (shfl), then per-cached-edge weights w=exp(e-m)
// and lsum (shfl) IN PARALLEL; the sequential pass 2 is loads+unpack+FMA only,
// with wave-uniform (SGPR) src index and weight.

template<int OUT, bool FTBF, bool FINAL>
__global__ __launch_bounds__(256) void k_agg(const void* __restrict__ ftv, const float* __restrict__ el,
                                             const float* __restrict__ er, const int* __restrict__ rowptr,
                                             const int* __restrict__ csrsrc, const void* __restrict__ bias,
                                             const int* __restrict__ dflag, void* __restrict__ outp){
    const int isbf = *dflag;
    int lane = threadIdx.x & 63;
    int n = blockIdx.x * 4 + (threadIdx.x >> 6);
    if (n >= NN) return;
    int beg = rowptr[n], end = rowptr[n + 1];
    beg = (beg < 0) ? 0 : (beg > NE ? NE : beg);        // defensive clamps
    end = (end < beg) ? beg : (end > NE ? NE : end);
    int deg = end - beg;
    float erd = er[n];

    // Pass 1: parallel logits + max; cache first 64 (src, logit) in registers.
    float m = -3.4e38f;
    int   s_c = 0;
    float e_c = 0.f;
    for (int i = beg + lane; i < end; i += 64){
        int s = csrsrc[i];
        if ((unsigned)s >= NN) s = 0;
        float e = el[s] + erd;
        e = (e >= 0.f) ? e : 0.2f * e;       // LeakyReLU, slope 0.2
        if (i < beg + 64){ s_c = s; e_c = e; }
        m = fmaxf(m, e);
    }
    #pragma unroll
    for (int off = 32; off; off >>= 1) m = fmaxf(m, __shfl_xor(m, off));

    int jmax = (deg < 64) ? deg : 64;
    // Parallel weights for the cached edges; zero on inactive lanes.
    float w_c = (lane < jmax) ? __expf(e_c - m) : 0.f;
    float lsum = w_c;
    #pragma unroll
    for (int off = 32; off; off >>= 1) lsum += __shfl_xor(lsum, off);

    if constexpr (OUT == 128){
        // 128 features over 64 lanes, bf16-packed; 4x unrolled, scalar-pipe addressing.
        const unsigned* ftb = (const unsigned*)ftv;
        float acc0 = 0.f, acc1 = 0.f;
        int j = 0;
        for (; j + 4 <= jmax; j += 4){
            int s0 = __builtin_amdgcn_readlane(s_c, j);
            int s1 = __builtin_amdgcn_readlane(s_c, j + 1);
            int s2 = __builtin_amdgcn_readlane(s_c, j + 2);
            int s3 = __builtin_amdgcn_readlane(s_c, j + 3);
            float w0 = rdlanef(w_c, j);
            float w1 = rdlanef(w_c, j + 1);
            float w2 = rdlanef(w_c, j + 2);
            float w3 = rdlanef(w_c, j + 3);
            unsigned u0 = (ftb + s0 * 64)[lane];
            unsigned u1 = (ftb + s1 * 64)[lane];
            unsigned u2 = (ftb + s2 * 64)[lane];
            unsigned u3 = (ftb + s3 * 64)[lane];
            acc0 += w0 * bflo(u0); acc1 += w0 * bfhi(u0);
            acc0 += w1 * bflo(u1); acc1 += w1 * bfhi(u1);
            acc0 += w2 * bflo(u2); acc1 += w2 * bfhi(u2);
            acc0 += w3 * bflo(u3); acc1 += w3 * bfhi(u3);
        }
        for (; j < jmax; ++j){
            int s = __builtin_amdgcn_readlane(s_c, j);
            float w = rdlanef(w_c, j);
            unsigned u = (ftb + s * 64)[lane];
            acc0 += w * bflo(u); acc1 += w * bfhi(u);
        }
        // Rare tail (deg > 64)
        for (int i = beg + 64; i < end; ++i){
            int s = csrsrc[i];
            if ((unsigned)s >= NN) s = 0;
            float e = el[s] + erd;
            e = (e >= 0.f) ? e : 0.2f * e;
            float w = __expf(e - m);
            unsigned u = (ftb + s * 64)[lane];
            lsum += w;
            acc0 += w * bflo(u); acc1 += w * bfhi(u);
        }
        float inv = 1.f / ((lsum > 0.f) ? lsum : 1.f);
        float2 o;
        o.x = fmaxf(acc0 * inv + ldf(bias, 2 * lane,     isbf), 0.f);
        o.y = fmaxf(acc1 * inv + ldf(bias, 2 * lane + 1, isbf), 0.f);
        ((float2*)outp)[n * 64 + lane] = o;
    } else {
        // OUT==16, f32 ft: 4 lane-groups of 16 process 4 edges per iteration.
        const float* ftf = (const float*)ftv;
        int g  = lane >> 4;       // edge group 0..3
        int fl = lane & 15;       // feature
        float acc0 = 0.f;
        int j = 0;
        for (; j + 4 <= jmax; j += 4){
            int   s = __shfl(s_c, j + g);
            float w = __shfl(w_c, j + g);
            acc0 += w * ftf[s * 16 + fl];
        }
        for (; j < jmax; ++j){
            int s = __builtin_amdgcn_readlane(s_c, j);
            float w = rdlanef(w_c, j);
            if (g == 0) acc0 += w * ftf[s * 16 + fl];
        }
        for (int i = beg + 64; i < end; ++i){
            int s = csrsrc[i];
            if ((unsigned)s >= NN) s = 0;
            float e = el[s] + erd;
            e = (e >= 0.f) ? e : 0.2f * e;
            float w = __expf(e - m);
            lsum += w;
            if (g == 0) acc0 += w * ftf[s * 16 + fl];
        }
        // reduce over the 4 edge groups (bits 4,5 of lane)
        acc0 += __shfl_xor(acc0, 16); acc0 += __shfl_xor(acc0, 32);
        float inv = 1.f / ((lsum > 0.f) ? lsum : 1.f);
        if (lane < 16){
            float o = fmaxf(acc0 * inv + ldf(bias, fl, isbf), 0.f);
            if (FINAL && isbf) ((bf16*)outp)[n * 16 + fl] = __float2bfloat16(o);
            else               ((float*)outp)[n * 16 + fl] = o;
        }
    }
}

// ---------------- host launch ----------------

static size_t align256(size_t x){ return (x + 255) & ~(size_t)255; }

extern "C" void kernel_launch(void* const* d_in, const int* in_sizes, int n_in,
                              void* d_out, int out_size, void* d_ws, size_t ws_size,
                              hipStream_t stream) {
    const void* feat = d_in[0];
    const int*  src  = (const int*)d_in[1];
    const int*  dst  = (const int*)d_in[2];
    const void* W1 = d_in[3];
    const void* al1= d_in[4];
    const void* ar1= d_in[5];
    const void* b1 = d_in[6];
    const void* W2 = d_in[7];
    const void* al2= d_in[8];
    const void* ar2= d_in[9];
    const void* b2 = d_in[10];
    const void* W3 = d_in[11];
    const void* al3= d_in[12];
    const void* ar3= d_in[13];
    const void* b3 = d_in[14];

    // workspace carve
    char* p = (char*)d_ws;
    size_t off = 0;
    auto carve = [&](size_t bytes)->void*{
        void* r = p + off;
        off += align256(bytes);
        return r;
    };
    float* ftA   = (float*)carve((size_t)NN * FF * 4);   // ft buffer: bf16 view (layers 1/2), f32 view (layer 3)
    float* hB    = (float*)carve((size_t)NN * FF * 4);   // hidden state; bpairs overlays it pre-layer-1
    float* el    = (float*)carve((size_t)NN * 4);
    float* er    = (float*)carve((size_t)NN * 4);
    int*   rowptr= (int*)  carve((size_t)(NN + 1) * 4);
    int*   csrsrc= (int*)  carve((size_t)NE * 4);
    int*   bcounts=(int*)  carve((size_t)NB * 4);
    int*   bbase  =(int*)  carve((size_t)(NB + 1) * 4);
    int*   bh     =(int*)  carve((size_t)NB * NBLK * 4);  // per-(bucket,block) hist/offsets, 400KB
    int*   dflag  =(int*)  carve(256);
    unsigned* bpairs = (unsigned*)hB;   // overlay: consumed before hB is first written
    void*  ftb   = ftA;                 // bf16 ft view (layers 1-2); f32 ft3 view (layer 3)
    (void)ws_size; (void)n_in; (void)in_sizes; (void)out_size;

    dim3 b256(256);

    // dtype detection (inputs are either all-f32 or all-bf16)
    k_detect<<<dim3(1), b256, 0, stream>>>((const unsigned short*)feat, dflag);

    // CSR build via hierarchical counting sort (every call: ws is re-poisoned)
    k_zero<<<dim3((NB + 255) / 256), b256, 0, stream>>>(bcounts, NB);
    k_bcount<<<dim3(NBLK), b256, 0, stream>>>(dst, bcounts, bh);
    k_bscan<<<dim3(1), b256, 0, stream>>>(bcounts, bbase, rowptr);
    k_boffset<<<dim3((NB + 3) / 4), b256, 0, stream>>>(bbase, bh);
    k_bucket<<<dim3(NBLK), b256, 0, stream>>>(src, dst, bh, bpairs);
    k_bsort<<<dim3(NB), b256, 0, stream>>>(bpairs, bbase, rowptr, csrsrc);

    const int gemm_grid = (NN + 15) / 16;     // 3125
    const int node_grid = (NN + 3) / 4;       // 12500

    // Layer 1: feat @ W1 -> ftb (bf16); agg -> hB (f32)
    k_gemm<true, 128, 8, true><<<dim3(gemm_grid), b256, 0, stream>>>(feat, W1, dflag, ftb);
    k_el_er<128, true><<<dim3(node_grid), b256, 0, stream>>>(ftb, al1, ar1, dflag, el, er);
    k_agg<128, true, false><<<dim3(node_grid), b256, 0, stream>>>(ftb, el, er, rowptr, csrsrc, b1, dflag, hB);

    // Layer 2: hB @ W2 -> ftb (bf16); agg -> hB
    k_gemm<false, 128, 8, true><<<dim3(gemm_grid), b256, 0, stream>>>(hB, W2, dflag, ftb);
    k_el_er<128, true><<<dim3(node_grid), b256, 0, stream>>>(ftb, al2, ar2, dflag, el, er);
    k_agg<128, true, false><<<dim3(node_grid), b256, 0, stream>>>(ftb, el, er, rowptr, csrsrc, b2, dflag, hB);

    // Layer 3 (all f32): hB @ W3 -> ft3; agg -> d_out
    k_gemm<false, 16, 1, false><<<dim3(gemm_grid), b256, 0, stream>>>(hB, W3, dflag, ftb);
    k_el_er<16, false><<<dim3(node_grid), b256, 0, stream>>>(ftb, al3, ar3, dflag, el, er);
    k_agg<16, false, true><<<dim3(node_grid), b256, 0, stream>>>(ftb, el, er, rowptr, csrsrc, b3, dflag, d_out);
}

// Round 8
// 447.707 us; speedup vs baseline: 1.0088x; 1.0088x over previous
//
#include <hip/hip_runtime.h>
#include <hip/hip_bf16.h>

#define NN 50000
#define NE 1600000
#define FF 128
#define CC 16
#define NB ((NN + 63) / 64)       // 782 dst-buckets of 64 nodes
#define NBLK 128                  // partition blocks for the sort
#define CH ((NE + NBLK - 1) / NBLK)   // 12500 edges per partition block

using bf16 = __hip_bfloat16;

// Runtime-dtype load: isbf selects bf16 vs f32 interpretation of p.
static __device__ __forceinline__ float ldf(const void* p, int i, int isbf){
    return isbf ? __bfloat162float(((const bf16*)p)[i]) : ((const float*)p)[i];
}
// Unpack a uint holding two bf16 (features 2k, 2k+1).
static __device__ __forceinline__ float bflo(unsigned u){
    union{unsigned x; float f;} c; c.x = u << 16; return c.f;
}
static __device__ __forceinline__ float bfhi(unsigned u){
    union{unsigned x; float f;} c; c.x = u & 0xFFFF0000u; return c.f;
}
static __device__ __forceinline__ float rdlanef(float v, int l){
    return __int_as_float(__builtin_amdgcn_readlane(__float_as_int(v), l));
}

// ---------------- dtype detector ----------------
__global__ __launch_bounds__(256) void k_detect(const unsigned short* __restrict__ u,
                                                int* __restrict__ flag){
    int t = threadIdx.x;
    unsigned short lo = u[2 * t];
    int e = (lo >> 7) & 0xFF;
    int sane = (e >= 117 && e <= 137) ? 1 : 0;
    __shared__ int cnt;
    if (t == 0) cnt = 0;
    __syncthreads();
    atomicAdd(&cnt, sane);
    __syncthreads();
    if (t == 0) *flag = (cnt >= 128) ? 1 : 0;   // 1 => bf16 data
}

__global__ __launch_bounds__(256) void k_zero(int* __restrict__ p, int n){
    int i = blockIdx.x * 256 + threadIdx.x;
    if (i < n) p[i] = 0;
}

// ---------------- CSR build: hierarchical counting sort by dst ----------------

__global__ __launch_bounds__(256) void k_bcount(const int* __restrict__ dst, int* __restrict__ bcounts,
                                                int* __restrict__ bh){
    __shared__ int hist[NB];
    const int t = threadIdx.x, b = blockIdx.x;
    for (int i = t; i < NB; i += 256) hist[i] = 0;
    __syncthreads();
    const int beg = b * CH, end = (beg + CH < NE) ? beg + CH : NE;
    for (int i = beg + t; i < end; i += 256){
        int d = dst[i];
        if ((unsigned)d >= NN) d = 0;
        atomicAdd(&hist[d >> 6], 1);
    }
    __syncthreads();
    for (int k = t; k < NB; k += 256){
        int v = hist[k];
        bh[k * NBLK + b] = v;
        if (v) atomicAdd(&bcounts[k], v);
    }
}

__global__ __launch_bounds__(256) void k_bscan(const int* __restrict__ bcounts, int* __restrict__ bbase,
                                               int* __restrict__ rowptr){
    __shared__ int s[256];
    const int t = threadIdx.x;
    constexpr int PT = (NB + 255) / 256;   // 4
    int loc[PT];
    int sum = 0;
    #pragma unroll
    for (int i = 0; i < PT; i++){
        int idx = t * PT + i;
        int v = (idx < NB) ? bcounts[idx] : 0;
        loc[i] = sum;
        sum += v;
    }
    s[t] = sum; __syncthreads();
    for (int off = 1; off < 256; off <<= 1){
        int x = (t >= off) ? s[t - off] : 0;
        __syncthreads();
        s[t] += x;
        __syncthreads();
    }
    int base = (t > 0) ? s[t - 1] : 0;
    #pragma unroll
    for (int i = 0; i < PT; i++){
        int idx = t * PT + i;
        if (idx < NB) bbase[idx] = base + loc[i];
    }
    if (t == 255){
        bbase[NB] = s[255];      // == NE
        rowptr[NN] = s[255];
    }
}

// Per-bucket offsets: wave-per-bucket shfl scan over the 128 per-block counts.
__global__ __launch_bounds__(256) void k_boffset(const int* __restrict__ bbase, int* __restrict__ bh){
    int k = blockIdx.x * 4 + (threadIdx.x >> 6);
    int lane = threadIdx.x & 63;
    if (k >= NB) return;
    int v0 = bh[k * NBLK + 2 * lane];
    int v1 = bh[k * NBLK + 2 * lane + 1];
    int s = v0 + v1;
    #pragma unroll
    for (int off = 1; off < 64; off <<= 1){
        int x = __shfl_up(s, off);
        if (lane >= off) s += x;
    }
    int base = bbase[k] + s - (v0 + v1);   // exclusive prefix of pair sums
    bh[k * NBLK + 2 * lane]     = base;
    bh[k * NBLK + 2 * lane + 1] = base + v0;
}

__global__ __launch_bounds__(256) void k_bucket(const int* __restrict__ src, const int* __restrict__ dst,
                                                const int* __restrict__ bh, unsigned* __restrict__ bpairs){
    __shared__ int cur[NB];
    const int t = threadIdx.x, b = blockIdx.x;
    for (int k = t; k < NB; k += 256) cur[k] = bh[k * NBLK + b];
    __syncthreads();
    const int beg = b * CH, end = (beg + CH < NE) ? beg + CH : NE;
    for (int i = beg + t; i < end; i += 256){
        int s = src[i];
        int d = dst[i];
        if ((unsigned)s >= NN) s = 0;
        if ((unsigned)d >= NN) d = 0;
        int p = atomicAdd(&cur[d >> 6], 1);
        if ((unsigned)p < NE) bpairs[p] = (unsigned)s | ((unsigned)(d & 63) << 16);
    }
}

__global__ __launch_bounds__(256) void k_bsort(const unsigned* __restrict__ bpairs, const int* __restrict__ bbase,
                                               int* __restrict__ rowptr, int* __restrict__ csrsrc){
    __shared__ int cnt[64];
    __shared__ int cur[64];
    const int t = threadIdx.x;
    const int b = blockIdx.x;
    const int base = bbase[b];
    const int endb = bbase[b + 1];
    if (t < 64) cnt[t] = 0;
    __syncthreads();
    for (int i = base + t; i < endb; i += 256)
        atomicAdd(&cnt[bpairs[i] >> 16], 1);
    __syncthreads();
    if (t < 64){   // wave 0 exactly: 64-lane exclusive scan via shfl
        int v = cnt[t];
        int inc = v;
        #pragma unroll
        for (int off = 1; off < 64; off <<= 1){
            int x = __shfl_up(inc, off);
            if (t >= off) inc += x;
        }
        int excl = inc - v;
        cur[t] = excl;
        int d = b * 64 + t;
        if (d < NN) rowptr[d] = base + excl;
    }
    __syncthreads();
    for (int i = base + t; i < endb; i += 256){
        unsigned pr = bpairs[i];
        int p = atomicAdd(&cur[pr >> 16], 1);
        csrsrc[base + p] = (int)(pr & 0xFFFFu);
    }
}

// ---------------- GEMM + fused el/er: ft = X @ W; el = ft.al; er = ft.ar ----------------
// Each block computes COMPLETE rows for its BN=16 nodes, so the attention dots
// reduce entirely within the block (shfl + tiny LDS combine).

template<bool XDYN, int OUT, int NPT, bool FTBF>
__global__ __launch_bounds__(256) void k_gemm(const void* __restrict__ X, const void* __restrict__ W,
                                              const void* __restrict__ al, const void* __restrict__ ar,
                                              const int* __restrict__ dflag, void* __restrict__ ft,
                                              float* __restrict__ el, float* __restrict__ er){
    constexpr int BN = 256 * NPT / OUT;   // 16 for both instantiations
    __shared__ float xs[FF][BN + 1];      // transposed, +1 pad kills store conflicts
    __shared__ float pel[BN][2], per[BN][2];
    const int isbf = *dflag;
    const int t  = threadIdx.x;
    const int n0 = blockIdx.x * BN;

    for (int idx = t; idx < BN * FF; idx += 256){
        int r = idx >> 7;        // node within tile
        int c = idx & 127;       // feature
        int n = n0 + r;
        float v = 0.f;
        if (n < NN){
            if (XDYN) v = ldf(X, n * FF + c, isbf);
            else      v = ((const float*)X)[n * FF + c];
        }
        xs[c][r] = v;
    }
    __syncthreads();

    const int tx = t % OUT;
    const int rg = t / OUT;      // row group
    float acc[NPT];
    #pragma unroll
    for (int i = 0; i < NPT; i++) acc[i] = 0.f;

    if (isbf){
        const bf16* Wb = (const bf16*)W;
        for (int k = 0; k < FF; k++){
            float w = __bfloat162float(Wb[k * OUT + tx]);
            #pragma unroll
            for (int i = 0; i < NPT; i++) acc[i] += w * xs[k][rg * NPT + i];
        }
    } else {
        const float* Wf = (const float*)W;
        for (int k = 0; k < FF; k++){
            float w = Wf[k * OUT + tx];
            #pragma unroll
            for (int i = 0; i < NPT; i++) acc[i] += w * xs[k][rg * NPT + i];
        }
    }

    #pragma unroll
    for (int i = 0; i < NPT; i++){
        int n = n0 + rg * NPT + i;
        if (n < NN){
            if (FTBF) ((bf16*)ft)[n * OUT + tx] = __float2bfloat16(acc[i]);
            else      ((float*)ft)[n * OUT + tx] = acc[i];
        }
    }

    // ---- fused el/er ----
    float alv = ldf(al, tx, isbf);
    float arv = ldf(ar, tx, isbf);
    if (OUT == 128){
        int wig = (t >> 6) & 1;          // wave within row-group (2 waves cover 128 cols)
        #pragma unroll
        for (int i = 0; i < NPT; i++){
            float pl = acc[i] * alv, pr = acc[i] * arv;
            #pragma unroll
            for (int off = 32; off; off >>= 1){
                pl += __shfl_xor(pl, off);
                pr += __shfl_xor(pr, off);
            }
            if ((t & 63) == 0){
                pel[rg * NPT + i][wig] = pl;
                per[rg * NPT + i][wig] = pr;
            }
        }
        __syncthreads();
        if (t < BN){
            int n = n0 + t;
            if (n < NN){
                el[n] = pel[t][0] + pel[t][1];
                er[n] = per[t][0] + per[t][1];
            }
        }
    } else {
        // OUT==16: 16-lane groups hold a full row; reduce within quarter-wave.
        float pl = acc[0] * alv, pr = acc[0] * arv;
        #pragma unroll
        for (int off = 1; off < 16; off <<= 1){
            pl += __shfl_xor(pl, off);
            pr += __shfl_xor(pr, off);
        }
        int n = n0 + rg;
        if (tx == 0 && n < NN){ el[n] = pl; er[n] = pr; }
    }
}

// ---------------- Aggregation: one wave per dst node, edge softmax + weighted sum ----------------
// Pass 1: parallel logits/max/weights/lsum. Pass 2 (OUT=128): 8-deep
// software-pipelined row gather — next batch's loads issue before current
// batch is consumed, keeping 8 loads in flight per wave.

template<int OUT, bool FTBF, bool FINAL>
__global__ __launch_bounds__(256) void k_agg(const void* __restrict__ ftv, const float* __restrict__ el,
                                             const float* __restrict__ er, const int* __restrict__ rowptr,
                                             const int* __restrict__ csrsrc, const void* __restrict__ bias,
                                             const int* __restrict__ dflag, void* __restrict__ outp){
    const int isbf = *dflag;
    int lane = threadIdx.x & 63;
    int n = blockIdx.x * 4 + (threadIdx.x >> 6);
    if (n >= NN) return;
    int beg = rowptr[n], end = rowptr[n + 1];
    beg = (beg < 0) ? 0 : (beg > NE ? NE : beg);        // defensive clamps
    end = (end < beg) ? beg : (end > NE ? NE : end);
    int deg = end - beg;
    float erd = er[n];

    // Pass 1: parallel logits + max; cache first 64 (src, logit) in registers.
    float m = -3.4e38f;
    int   s_c = 0;
    float e_c = 0.f;
    for (int i = beg + lane; i < end; i += 64){
        int s = csrsrc[i];
        if ((unsigned)s >= NN) s = 0;
        float e = el[s] + erd;
        e = (e >= 0.f) ? e : 0.2f * e;       // LeakyReLU, slope 0.2
        if (i < beg + 64){ s_c = s; e_c = e; }
        m = fmaxf(m, e);
    }
    #pragma unroll
    for (int off = 32; off; off >>= 1) m = fmaxf(m, __shfl_xor(m, off));

    int jmax = (deg < 64) ? deg : 64;
    float w_c = (lane < jmax) ? __expf(e_c - m) : 0.f;
    float lsum = w_c;
    #pragma unroll
    for (int off = 32; off; off >>= 1) lsum += __shfl_xor(lsum, off);

    if constexpr (OUT == 128){
        const unsigned* ftb = (const unsigned*)ftv;
        float acc0 = 0.f, acc1 = 0.f;
        int j = 0;
        if (jmax >= 8){
            float w[8]; unsigned u[8];
            #pragma unroll
            for (int q = 0; q < 8; q++){
                int s = __builtin_amdgcn_readlane(s_c, q);
                w[q] = rdlanef(w_c, q);
                u[q] = (ftb + s * 64)[lane];
            }
            for (j = 8; j + 8 <= jmax; j += 8){
                float wn[8]; unsigned un[8];
                #pragma unroll
                for (int q = 0; q < 8; q++){
                    int s = __builtin_amdgcn_readlane(s_c, j + q);
                    wn[q] = rdlanef(w_c, j + q);
                    un[q] = (ftb + s * 64)[lane];
                }
                #pragma unroll
                for (int q = 0; q < 8; q++){
                    acc0 += w[q] * bflo(u[q]);
                    acc1 += w[q] * bfhi(u[q]);
                    w[q] = wn[q]; u[q] = un[q];
                }
            }
            #pragma unroll
            for (int q = 0; q < 8; q++){
                acc0 += w[q] * bflo(u[q]);
                acc1 += w[q] * bfhi(u[q]);
            }
        }
        for (; j < jmax; ++j){
            int s = __builtin_amdgcn_readlane(s_c, j);
            float w = rdlanef(w_c, j);
            unsigned u = (ftb + s * 64)[lane];
            acc0 += w * bflo(u); acc1 += w * bfhi(u);
        }
        // Rare tail (deg > 64)
        for (int i = beg + 64; i < end; ++i){
            int s = csrsrc[i];
            if ((unsigned)s >= NN) s = 0;
            float e = el[s] + erd;
            e = (e >= 0.f) ? e : 0.2f * e;
            float w = __expf(e - m);
            unsigned u = (ftb + s * 64)[lane];
            lsum += w;
            acc0 += w * bflo(u); acc1 += w * bfhi(u);
        }
        float inv = 1.f / ((lsum > 0.f) ? lsum : 1.f);
        float2 o;
        o.x = fmaxf(acc0 * inv + ldf(bias, 2 * lane,     isbf), 0.f);
        o.y = fmaxf(acc1 * inv + ldf(bias, 2 * lane + 1, isbf), 0.f);
        ((float2*)outp)[n * 64 + lane] = o;
    } else {
        // OUT==16, f32 ft: 4 lane-groups of 16 process 4 edges per iteration.
        const float* ftf = (const float*)ftv;
        int g  = lane >> 4;       // edge group 0..3
        int fl = lane & 15;       // feature
        float acc0 = 0.f;
        int j = 0;
        for (; j + 4 <= jmax; j += 4){
            int   s = __shfl(s_c, j + g);
            float w = __shfl(w_c, j + g);
            acc0 += w * ftf[s * 16 + fl];
        }
        for (; j < jmax; ++j){
            int s = __builtin_amdgcn_readlane(s_c, j);
            float w = rdlanef(w_c, j);
            if (g == 0) acc0 += w * ftf[s * 16 + fl];
        }
        for (int i = beg + 64; i < end; ++i){
            int s = csrsrc[i];
            if ((unsigned)s >= NN) s = 0;
            float e = el[s] + erd;
            e = (e >= 0.f) ? e : 0.2f * e;
            float w = __expf(e - m);
            lsum += w;
            if (g == 0) acc0 += w * ftf[s * 16 + fl];
        }
        // reduce over the 4 edge groups (bits 4,5 of lane)
        acc0 += __shfl_xor(acc0, 16); acc0 += __shfl_xor(acc0, 32);
        float inv = 1.f / ((lsum > 0.f) ? lsum : 1.f);
        if (lane < 16){
            float o = fmaxf(acc0 * inv + ldf(bias, fl, isbf), 0.f);
            if (FINAL && isbf) ((bf16*)outp)[n * 16 + fl] = __float2bfloat16(o);
            else               ((float*)outp)[n * 16 + fl] = o;
        }
    }
}

// ---------------- host launch ----------------

static size_t align256(size_t x){ return (x + 255) & ~(size_t)255; }

extern "C" void kernel_launch(void* const* d_in, const int* in_sizes, int n_in,
                              void* d_out, int out_size, void* d_ws, size_t ws_size,
                              hipStream_t stream) {
    const void* feat = d_in[0];
    const int*  src  = (const int*)d_in[1];
    const int*  dst  = (const int*)d_in[2];
    const void* W1 = d_in[3];
    const void* al1= d_in[4];
    const void* ar1= d_in[5];
    const void* b1 = d_in[6];
    const void* W2 = d_in[7];
    const void* al2= d_in[8];
    const void* ar2= d_in[9];
    const void* b2 = d_in[10];
    const void* W3 = d_in[11];
    const void* al3= d_in[12];
    const void* ar3= d_in[13];
    const void* b3 = d_in[14];

    // workspace carve
    char* p = (char*)d_ws;
    size_t off = 0;
    auto carve = [&](size_t bytes)->void*{
        void* r = p + off;
        off += align256(bytes);
        return r;
    };
    float* ftA   = (float*)carve((size_t)NN * FF * 4);   // ft buffer: bf16 view (layers 1/2), f32 view (layer 3)
    float* hB    = (float*)carve((size_t)NN * FF * 4);   // hidden state; bpairs overlays it pre-layer-1
    float* el    = (float*)carve((size_t)NN * 4);
    float* er    = (float*)carve((size_t)NN * 4);
    int*   rowptr= (int*)  carve((size_t)(NN + 1) * 4);
    int*   csrsrc= (int*)  carve((size_t)NE * 4);
    int*   bcounts=(int*)  carve((size_t)NB * 4);
    int*   bbase  =(int*)  carve((size_t)(NB + 1) * 4);
    int*   bh     =(int*)  carve((size_t)NB * NBLK * 4);  // per-(bucket,block) hist/offsets, 400KB
    int*   dflag  =(int*)  carve(256);
    unsigned* bpairs = (unsigned*)hB;   // overlay: consumed before hB is first written
    void*  ftb   = ftA;                 // bf16 ft view (layers 1-2); f32 ft3 view (layer 3)
    (void)ws_size; (void)n_in; (void)in_sizes; (void)out_size;

    dim3 b256(256);

    // dtype detection (inputs are either all-f32 or all-bf16)
    k_detect<<<dim3(1), b256, 0, stream>>>((const unsigned short*)feat, dflag);

    // CSR build via hierarchical counting sort (every call: ws is re-poisoned)
    k_zero<<<dim3((NB + 255) / 256), b256, 0, stream>>>(bcounts, NB);
    k_bcount<<<dim3(NBLK), b256, 0, stream>>>(dst, bcounts, bh);
    k_bscan<<<dim3(1), b256, 0, stream>>>(bcounts, bbase, rowptr);
    k_boffset<<<dim3((NB + 3) / 4), b256, 0, stream>>>(bbase, bh);
    k_bucket<<<dim3(NBLK), b256, 0, stream>>>(src, dst, bh, bpairs);
    k_bsort<<<dim3(NB), b256, 0, stream>>>(bpairs, bbase, rowptr, csrsrc);

    const int gemm_grid = (NN + 15) / 16;     // 3125
    const int node_grid = (NN + 3) / 4;       // 12500

    // Layer 1: feat @ W1 -> ftb (bf16) + el/er fused; agg -> hB (f32)
    k_gemm<true, 128, 8, true><<<dim3(gemm_grid), b256, 0, stream>>>(feat, W1, al1, ar1, dflag, ftb, el, er);
    k_agg<128, true, false><<<dim3(node_grid), b256, 0, stream>>>(ftb, el, er, rowptr, csrsrc, b1, dflag, hB);

    // Layer 2: hB @ W2 -> ftb (bf16) + el/er fused; agg -> hB
    k_gemm<false, 128, 8, true><<<dim3(gemm_grid), b256, 0, stream>>>(hB, W2, al2, ar2, dflag, ftb, el, er);
    k_agg<128, true, false><<<dim3(node_grid), b256, 0, stream>>>(ftb, el, er, rowptr, csrsrc, b2, dflag, hB);

    // Layer 3 (all f32): hB @ W3 -> ft3 + el/er fused; agg -> d_out
    k_gemm<false, 16, 1, false><<<dim3(gemm_grid), b256, 0, stream>>>(hB, W3, al3, ar3, dflag, ftb, el, er);
    k_agg<16, false, true><<<dim3(node_grid), b256, 0, stream>>>(ftb, el, er, rowptr, csrsrc, b3, dflag, d_out);
}

// Round 9
// 377.123 us; speedup vs baseline: 1.1976x; 1.1872x over previous
//
#include <hip/hip_runtime.h>
#include <hip/hip_bf16.h>

#define NN 50000
#define NE 1600000
#define FF 128
#define CC 16
#define NB ((NN + 63) / 64)       // 782 dst-buckets of 64 nodes
#define NBLK 128                  // partition blocks for the sort
#define CH ((NE + NBLK - 1) / NBLK)   // 12500 edges per partition block

using bf16 = __hip_bfloat16;
using bf16x8 = __attribute__((ext_vector_type(8))) short;   // 8 bf16 = 4 VGPRs
using f32x4  = __attribute__((ext_vector_type(4))) float;

// Runtime-dtype load: isbf selects bf16 vs f32 interpretation of p.
static __device__ __forceinline__ float ldf(const void* p, int i, int isbf){
    return isbf ? __bfloat162float(((const bf16*)p)[i]) : ((const float*)p)[i];
}
static __device__ __forceinline__ float bflo(unsigned u){
    union{unsigned x; float f;} c; c.x = u << 16; return c.f;
}
static __device__ __forceinline__ float bfhi(unsigned u){
    union{unsigned x; float f;} c; c.x = u & 0xFFFF0000u; return c.f;
}
static __device__ __forceinline__ float rdlanef(float v, int l){
    return __int_as_float(__builtin_amdgcn_readlane(__float_as_int(v), l));
}
static __device__ __forceinline__ unsigned short f2bfu(float v){
    bf16 b = __float2bfloat16(v);
    union{bf16 b; unsigned short u;} c; c.b = b; return c.u;
}

// ---------------- dtype detector ----------------
__global__ __launch_bounds__(256) void k_detect(const unsigned short* __restrict__ u,
                                                int* __restrict__ flag){
    int t = threadIdx.x;
    unsigned short lo = u[2 * t];
    int e = (lo >> 7) & 0xFF;
    int sane = (e >= 117 && e <= 137) ? 1 : 0;
    __shared__ int cnt;
    if (t == 0) cnt = 0;
    __syncthreads();
    atomicAdd(&cnt, sane);
    __syncthreads();
    if (t == 0) *flag = (cnt >= 128) ? 1 : 0;   // 1 => bf16 data
}

__global__ __launch_bounds__(256) void k_zero(int* __restrict__ p, int n){
    int i = blockIdx.x * 256 + threadIdx.x;
    if (i < n) p[i] = 0;
}

// ---------------- W prep: Wt[feat][k] = bf16(W[k][feat]) for W1, W2 ----------------
__global__ __launch_bounds__(256) void k_wprep(const void* __restrict__ W1, const void* __restrict__ W2,
                                               const int* __restrict__ dflag, unsigned short* __restrict__ wtg){
    const int isbf = *dflag;
    int idx = blockIdx.x * 256 + threadIdx.x;   // 0 .. 32767
    int l = idx >> 14;                          // 0: W1, 1: W2
    int e = idx & 16383;
    int f = e >> 7, k = e & 127;
    const void* W = l ? W2 : W1;
    wtg[idx] = f2bfu(ldf(W, k * FF + f, isbf));
}

// ---------------- CSR build: hierarchical counting sort by dst ----------------

__global__ __launch_bounds__(256) void k_bcount(const int* __restrict__ dst, int* __restrict__ bcounts,
                                                int* __restrict__ bh){
    __shared__ int hist[NB];
    const int t = threadIdx.x, b = blockIdx.x;
    for (int i = t; i < NB; i += 256) hist[i] = 0;
    __syncthreads();
    const int beg = b * CH, end = (beg + CH < NE) ? beg + CH : NE;
    for (int i = beg + t; i < end; i += 256){
        int d = dst[i];
        if ((unsigned)d >= NN) d = 0;
        atomicAdd(&hist[d >> 6], 1);
    }
    __syncthreads();
    for (int k = t; k < NB; k += 256){
        int v = hist[k];
        bh[k * NBLK + b] = v;
        if (v) atomicAdd(&bcounts[k], v);
    }
}

__global__ __launch_bounds__(256) void k_bscan(const int* __restrict__ bcounts, int* __restrict__ bbase,
                                               int* __restrict__ rowptr){
    __shared__ int s[256];
    const int t = threadIdx.x;
    constexpr int PT = (NB + 255) / 256;   // 4
    int loc[PT];
    int sum = 0;
    #pragma unroll
    for (int i = 0; i < PT; i++){
        int idx = t * PT + i;
        int v = (idx < NB) ? bcounts[idx] : 0;
        loc[i] = sum;
        sum += v;
    }
    s[t] = sum; __syncthreads();
    for (int off = 1; off < 256; off <<= 1){
        int x = (t >= off) ? s[t - off] : 0;
        __syncthreads();
        s[t] += x;
        __syncthreads();
    }
    int base = (t > 0) ? s[t - 1] : 0;
    #pragma unroll
    for (int i = 0; i < PT; i++){
        int idx = t * PT + i;
        if (idx < NB) bbase[idx] = base + loc[i];
    }
    if (t == 255){
        bbase[NB] = s[255];      // == NE
        rowptr[NN] = s[255];
    }
}

// Per-bucket offsets: wave-per-bucket shfl scan over the 128 per-block counts.
__global__ __launch_bounds__(256) void k_boffset(const int* __restrict__ bbase, int* __restrict__ bh){
    int k = blockIdx.x * 4 + (threadIdx.x >> 6);
    int lane = threadIdx.x & 63;
    if (k >= NB) return;
    int v0 = bh[k * NBLK + 2 * lane];
    int v1 = bh[k * NBLK + 2 * lane + 1];
    int s = v0 + v1;
    #pragma unroll
    for (int off = 1; off < 64; off <<= 1){
        int x = __shfl_up(s, off);
        if (lane >= off) s += x;
    }
    int base = bbase[k] + s - (v0 + v1);   // exclusive prefix of pair sums
    bh[k * NBLK + 2 * lane]     = base;
    bh[k * NBLK + 2 * lane + 1] = base + v0;
}

__global__ __launch_bounds__(256) void k_bucket(const int* __restrict__ src, const int* __restrict__ dst,
                                                const int* __restrict__ bh, unsigned* __restrict__ bpairs){
    __shared__ int cur[NB];
    const int t = threadIdx.x, b = blockIdx.x;
    for (int k = t; k < NB; k += 256) cur[k] = bh[k * NBLK + b];
    __syncthreads();
    const int beg = b * CH, end = (beg + CH < NE) ? beg + CH : NE;
    for (int i = beg + t; i < end; i += 256){
        int s = src[i];
        int d = dst[i];
        if ((unsigned)s >= NN) s = 0;
        if ((unsigned)d >= NN) d = 0;
        int p = atomicAdd(&cur[d >> 6], 1);
        if ((unsigned)p < NE) bpairs[p] = (unsigned)s | ((unsigned)(d & 63) << 16);
    }
}

__global__ __launch_bounds__(256) void k_bsort(const unsigned* __restrict__ bpairs, const int* __restrict__ bbase,
                                               int* __restrict__ rowptr, int* __restrict__ csrsrc){
    __shared__ int cnt[64];
    __shared__ int cur[64];
    const int t = threadIdx.x;
    const int b = blockIdx.x;
    const int base = bbase[b];
    const int endb = bbase[b + 1];
    if (t < 64) cnt[t] = 0;
    __syncthreads();
    for (int i = base + t; i < endb; i += 256)
        atomicAdd(&cnt[bpairs[i] >> 16], 1);
    __syncthreads();
    if (t < 64){   // wave 0 exactly: 64-lane exclusive scan via shfl
        int v = cnt[t];
        int inc = v;
        #pragma unroll
        for (int off = 1; off < 64; off <<= 1){
            int x = __shfl_up(inc, off);
            if (t >= off) inc += x;
        }
        int excl = inc - v;
        cur[t] = excl;
        int d = b * 64 + t;
        if (d < NN) rowptr[d] = base + excl;
    }
    __syncthreads();
    for (int i = base + t; i < endb; i += 256){
        unsigned pr = bpairs[i];
        int p = atomicAdd(&cur[pr >> 16], 1);
        csrsrc[base + p] = (int)(pr & 0xFFFFu);
    }
}

// ---------------- MFMA GEMM (layers 1-2): ft = X @ W, bf16 in / f32 acc / bf16 out ----------------
// Block: 256 thr = 4 waves, 64 nodes x 128 feats. LDS: X tile 64x(128+8) bf16,
// Wt tile 128x(128+8) bf16 (pad 8 -> fragment reads are 2-way bank aliased = free).
// Wave w: nodes [n0+16w, +16). A-frag layout A[m=lane&15][k=quad*8+j]; B from
// Wt[feat][k] so B[n=lane&15][k=quad*8+j] reads are contiguous. C/D: col=lane&15,
// row=quad*4+reg (m89-verified). el/er fused from f32 accumulators.

#define XPAD 136   // 17*8: keeps 16B alignment, breaks bank stride

template<bool XDYN>
__global__ __launch_bounds__(256) void k_mgemm(const void* __restrict__ X, const unsigned short* __restrict__ wtg,
                                               const void* __restrict__ al, const void* __restrict__ ar,
                                               const int* __restrict__ dflag, bf16* __restrict__ ft,
                                               float* __restrict__ el, float* __restrict__ er){
    __shared__ unsigned short xs[64 * XPAD];
    __shared__ unsigned short wt[128 * XPAD];
    const int isbf = *dflag;
    const int t  = threadIdx.x;
    const int n0 = blockIdx.x * 64;

    // Stage Wt (bf16, 16384 elems) as uint pairs.
    for (int i2 = t; i2 < 8192; i2 += 256){
        unsigned v = ((const unsigned*)wtg)[i2];
        int r = i2 >> 6, c2 = (i2 & 63) * 2;
        *(unsigned*)&wt[r * XPAD + c2] = v;
    }
    // Stage X tile (64 x 128), f32(or dyn)->bf16, as uint pairs.
    for (int i2 = t; i2 < 4096; i2 += 256){
        int r = i2 >> 6, c2 = (i2 & 63) * 2;
        int n = n0 + r;
        float v0 = 0.f, v1 = 0.f;
        if (n < NN){
            if (XDYN){ v0 = ldf(X, n * FF + c2, isbf); v1 = ldf(X, n * FF + c2 + 1, isbf); }
            else     { v0 = ((const float*)X)[n * FF + c2]; v1 = ((const float*)X)[n * FF + c2 + 1]; }
        }
        unsigned pk = (unsigned)f2bfu(v0) | ((unsigned)f2bfu(v1) << 16);
        *(unsigned*)&xs[r * XPAD + c2] = pk;
    }
    __syncthreads();

    const int wv = t >> 6;
    const int lane = t & 63;
    const int quad = lane >> 4;
    const int mcol = lane & 15;      // A-row / B-col / D-col index

    // A fragments: row (wv*16+mcol), 4 k-steps of 32.
    bf16x8 afr[4];
    const unsigned short* xrow = &xs[(wv * 16 + mcol) * XPAD + quad * 8];
    #pragma unroll
    for (int kt = 0; kt < 4; kt++)
        afr[kt] = *(const bf16x8*)(xrow + kt * 32);

    float elp[4] = {0.f,0.f,0.f,0.f}, erp[4] = {0.f,0.f,0.f,0.f};

    #pragma unroll
    for (int f = 0; f < 8; f++){
        f32x4 acc = {0.f, 0.f, 0.f, 0.f};
        const unsigned short* wrow = &wt[(f * 16 + mcol) * XPAD + quad * 8];
        #pragma unroll
        for (int kt = 0; kt < 4; kt++){
            bf16x8 bfr = *(const bf16x8*)(wrow + kt * 32);
            acc = __builtin_amdgcn_mfma_f32_16x16x32_bf16(afr[kt], bfr, acc, 0, 0, 0);
        }
        int col = f * 16 + mcol;
        float alv = ldf(al, col, isbf);
        float arv = ldf(ar, col, isbf);
        #pragma unroll
        for (int reg = 0; reg < 4; reg++){
            int node = n0 + wv * 16 + quad * 4 + reg;
            float v = acc[reg];
            if (node < NN) ft[node * FF + col] = __float2bfloat16(v);
            elp[reg] += v * alv;
            erp[reg] += v * arv;
        }
    }

    // Reduce el/er across the 16 cols (lanes within quad), write per node.
    #pragma unroll
    for (int reg = 0; reg < 4; reg++){
        float pl = elp[reg], pr = erp[reg];
        #pragma unroll
        for (int off = 1; off < 16; off <<= 1){
            pl += __shfl_xor(pl, off);
            pr += __shfl_xor(pr, off);
        }
        int node = n0 + wv * 16 + quad * 4 + reg;
        if (mcol == 0 && node < NN){ el[node] = pl; er[node] = pr; }
    }
}

// ---------------- vector GEMM + fused el/er (layer 3, OUT=16, f32) ----------------

template<bool XDYN, int OUT, int NPT, bool FTBF>
__global__ __launch_bounds__(256) void k_gemm(const void* __restrict__ X, const void* __restrict__ W,
                                              const void* __restrict__ al, const void* __restrict__ ar,
                                              const int* __restrict__ dflag, void* __restrict__ ft,
                                              float* __restrict__ el, float* __restrict__ er){
    constexpr int BN = 256 * NPT / OUT;   // 16
    __shared__ float xs[FF][BN + 1];      // transposed, +1 pad kills store conflicts
    const int isbf = *dflag;
    const int t  = threadIdx.x;
    const int n0 = blockIdx.x * BN;

    for (int idx = t; idx < BN * FF; idx += 256){
        int r = idx >> 7;        // node within tile
        int c = idx & 127;       // feature
        int n = n0 + r;
        float v = 0.f;
        if (n < NN){
            if (XDYN) v = ldf(X, n * FF + c, isbf);
            else      v = ((const float*)X)[n * FF + c];
        }
        xs[c][r] = v;
    }
    __syncthreads();

    const int tx = t % OUT;
    const int rg = t / OUT;      // row group
    float acc[NPT];
    #pragma unroll
    for (int i = 0; i < NPT; i++) acc[i] = 0.f;

    if (isbf){
        const bf16* Wb = (const bf16*)W;
        for (int k = 0; k < FF; k++){
            float w = __bfloat162float(Wb[k * OUT + tx]);
            #pragma unroll
            for (int i = 0; i < NPT; i++) acc[i] += w * xs[k][rg * NPT + i];
        }
    } else {
        const float* Wf = (const float*)W;
        for (int k = 0; k < FF; k++){
            float w = Wf[k * OUT + tx];
            #pragma unroll
            for (int i = 0; i < NPT; i++) acc[i] += w * xs[k][rg * NPT + i];
        }
    }

    #pragma unroll
    for (int i = 0; i < NPT; i++){
        int n = n0 + rg * NPT + i;
        if (n < NN){
            if (FTBF) ((bf16*)ft)[n * OUT + tx] = __float2bfloat16(acc[i]);
            else      ((float*)ft)[n * OUT + tx] = acc[i];
        }
    }

    // fused el/er (OUT==16: 16-lane groups hold a full row)
    float alv = ldf(al, tx, isbf);
    float arv = ldf(ar, tx, isbf);
    float pl = acc[0] * alv, pr = acc[0] * arv;
    #pragma unroll
    for (int off = 1; off < 16; off <<= 1){
        pl += __shfl_xor(pl, off);
        pr += __shfl_xor(pr, off);
    }
    int n = n0 + rg;
    if (tx == 0 && n < NN){ el[n] = pl; er[n] = pr; }
}

// ---------------- Aggregation: one wave per dst node, edge softmax + weighted sum ----------------

template<int OUT, bool FTBF, bool FINAL>
__global__ __launch_bounds__(256) void k_agg(const void* __restrict__ ftv, const float* __restrict__ el,
                                             const float* __restrict__ er, const int* __restrict__ rowptr,
                                             const int* __restrict__ csrsrc, const void* __restrict__ bias,
                                             const int* __restrict__ dflag, void* __restrict__ outp){
    const int isbf = *dflag;
    int lane = threadIdx.x & 63;
    int n = blockIdx.x * 4 + (threadIdx.x >> 6);
    if (n >= NN) return;
    int beg = rowptr[n], end = rowptr[n + 1];
    beg = (beg < 0) ? 0 : (beg > NE ? NE : beg);        // defensive clamps
    end = (end < beg) ? beg : (end > NE ? NE : end);
    int deg = end - beg;
    float erd = er[n];

    // Pass 1: parallel logits + max; cache first 64 (src, logit) in registers.
    float m = -3.4e38f;
    int   s_c = 0;
    float e_c = 0.f;
    for (int i = beg + lane; i < end; i += 64){
        int s = csrsrc[i];
        if ((unsigned)s >= NN) s = 0;
        float e = el[s] + erd;
        e = (e >= 0.f) ? e : 0.2f * e;       // LeakyReLU, slope 0.2
        if (i < beg + 64){ s_c = s; e_c = e; }
        m = fmaxf(m, e);
    }
    #pragma unroll
    for (int off = 32; off; off >>= 1) m = fmaxf(m, __shfl_xor(m, off));

    int jmax = (deg < 64) ? deg : 64;
    float w_c = (lane < jmax) ? __expf(e_c - m) : 0.f;
    float lsum = w_c;
    #pragma unroll
    for (int off = 32; off; off >>= 1) lsum += __shfl_xor(lsum, off);

    if constexpr (OUT == 128){
        const unsigned* ftb = (const unsigned*)ftv;
        float acc0 = 0.f, acc1 = 0.f;
        int j = 0;
        if (jmax >= 8){
            float w[8]; unsigned u[8];
            #pragma unroll
            for (int q = 0; q < 8; q++){
                int s = __builtin_amdgcn_readlane(s_c, q);
                w[q] = rdlanef(w_c, q);
                u[q] = (ftb + s * 64)[lane];
            }
            for (j = 8; j + 8 <= jmax; j += 8){
                float wn[8]; unsigned un[8];
                #pragma unroll
                for (int q = 0; q < 8; q++){
                    int s = __builtin_amdgcn_readlane(s_c, j + q);
                    wn[q] = rdlanef(w_c, j + q);
                    un[q] = (ftb + s * 64)[lane];
                }
                #pragma unroll
                for (int q = 0; q < 8; q++){
                    acc0 += w[q] * bflo(u[q]);
                    acc1 += w[q] * bfhi(u[q]);
                    w[q] = wn[q]; u[q] = un[q];
                }
            }
            #pragma unroll
            for (int q = 0; q < 8; q++){
                acc0 += w[q] * bflo(u[q]);
                acc1 += w[q] * bfhi(u[q]);
            }
        }
        for (; j < jmax; ++j){
            int s = __builtin_amdgcn_readlane(s_c, j);
            float w = rdlanef(w_c, j);
            unsigned u = (ftb + s * 64)[lane];
            acc0 += w * bflo(u); acc1 += w * bfhi(u);
        }
        // Rare tail (deg > 64)
        for (int i = beg + 64; i < end; ++i){
            int s = csrsrc[i];
            if ((unsigned)s >= NN) s = 0;
            float e = el[s] + erd;
            e = (e >= 0.f) ? e : 0.2f * e;
            float w = __expf(e - m);
            unsigned u = (ftb + s * 64)[lane];
            lsum += w;
            acc0 += w * bflo(u); acc1 += w * bfhi(u);
        }
        float inv = 1.f / ((lsum > 0.f) ? lsum : 1.f);
        float2 o;
        o.x = fmaxf(acc0 * inv + ldf(bias, 2 * lane,     isbf), 0.f);
        o.y = fmaxf(acc1 * inv + ldf(bias, 2 * lane + 1, isbf), 0.f);
        ((float2*)outp)[n * 64 + lane] = o;
    } else {
        // OUT==16, f32 ft: 4 lane-groups of 16 process 4 edges per iteration.
        const float* ftf = (const float*)ftv;
        int g  = lane >> 4;       // edge group 0..3
        int fl = lane & 15;       // feature
        float acc0 = 0.f;
        int j = 0;
        for (; j + 4 <= jmax; j += 4){
            int   s = __shfl(s_c, j + g);
            float w = __shfl(w_c, j + g);
            acc0 += w * ftf[s * 16 + fl];
        }
        for (; j < jmax; ++j){
            int s = __builtin_amdgcn_readlane(s_c, j);
            float w = rdlanef(w_c, j);
            if (g == 0) acc0 += w * ftf[s * 16 + fl];
        }
        for (int i = beg + 64; i < end; ++i){
            int s = csrsrc[i];
            if ((unsigned)s >= NN) s = 0;
            float e = el[s] + erd;
            e = (e >= 0.f) ? e : 0.2f * e;
            float w = __expf(e - m);
            lsum += w;
            if (g == 0) acc0 += w * ftf[s * 16 + fl];
        }
        acc0 += __shfl_xor(acc0, 16); acc0 += __shfl_xor(acc0, 32);
        float inv = 1.f / ((lsum > 0.f) ? lsum : 1.f);
        if (lane < 16){
            float o = fmaxf(acc0 * inv + ldf(bias, fl, isbf), 0.f);
            if (FINAL && isbf) ((bf16*)outp)[n * 16 + fl] = __float2bfloat16(o);
            else               ((float*)outp)[n * 16 + fl] = o;
        }
    }
}

// ---------------- host launch ----------------

static size_t align256(size_t x){ return (x + 255) & ~(size_t)255; }

extern "C" void kernel_launch(void* const* d_in, const int* in_sizes, int n_in,
                              void* d_out, int out_size, void* d_ws, size_t ws_size,
                              hipStream_t stream) {
    const void* feat = d_in[0];
    const int*  src  = (const int*)d_in[1];
    const int*  dst  = (const int*)d_in[2];
    const void* W1 = d_in[3];
    const void* al1= d_in[4];
    const void* ar1= d_in[5];
    const void* b1 = d_in[6];
    const void* W2 = d_in[7];
    const void* al2= d_in[8];
    const void* ar2= d_in[9];
    const void* b2 = d_in[10];
    const void* W3 = d_in[11];
    const void* al3= d_in[12];
    const void* ar3= d_in[13];
    const void* b3 = d_in[14];

    // workspace carve
    char* p = (char*)d_ws;
    size_t off = 0;
    auto carve = [&](size_t bytes)->void*{
        void* r = p + off;
        off += align256(bytes);
        return r;
    };
    float* ftA   = (float*)carve((size_t)NN * FF * 4);   // ft buffer: bf16 view (layers 1/2), f32 view (layer 3)
    float* hB    = (float*)carve((size_t)NN * FF * 4);   // hidden state; bpairs overlays it pre-layer-1
    float* el    = (float*)carve((size_t)NN * 4);
    float* er    = (float*)carve((size_t)NN * 4);
    int*   rowptr= (int*)  carve((size_t)(NN + 1) * 4);
    int*   csrsrc= (int*)  carve((size_t)NE * 4);
    int*   bcounts=(int*)  carve((size_t)NB * 4);
    int*   bbase  =(int*)  carve((size_t)(NB + 1) * 4);
    int*   bh     =(int*)  carve((size_t)NB * NBLK * 4);  // per-(bucket,block) hist/offsets, 400KB
    unsigned short* wtg = (unsigned short*)carve(2 * 16384 * 2);  // W1t,W2t bf16 [feat][k]
    int*   dflag  =(int*)  carve(256);
    unsigned* bpairs = (unsigned*)hB;   // overlay: consumed before hB is first written
    void*  ftb   = ftA;                 // bf16 ft view (layers 1-2); f32 ft3 view (layer 3)
    (void)ws_size; (void)n_in; (void)in_sizes; (void)out_size;

    dim3 b256(256);

    // dtype detection (inputs are either all-f32 or all-bf16)
    k_detect<<<dim3(1), b256, 0, stream>>>((const unsigned short*)feat, dflag);

    // Weight prep (after detect)
    k_wprep<<<dim3(128), b256, 0, stream>>>(W1, W2, dflag, wtg);

    // CSR build via hierarchical counting sort (every call: ws is re-poisoned)
    k_zero<<<dim3((NB + 255) / 256), b256, 0, stream>>>(bcounts, NB);
    k_bcount<<<dim3(NBLK), b256, 0, stream>>>(dst, bcounts, bh);
    k_bscan<<<dim3(1), b256, 0, stream>>>(bcounts, bbase, rowptr);
    k_boffset<<<dim3((NB + 3) / 4), b256, 0, stream>>>(bbase, bh);
    k_bucket<<<dim3(NBLK), b256, 0, stream>>>(src, dst, bh, bpairs);
    k_bsort<<<dim3(NB), b256, 0, stream>>>(bpairs, bbase, rowptr, csrsrc);

    const int mg_grid   = (NN + 63) / 64;     // 782
    const int gemm_grid = (NN + 15) / 16;     // 3125
    const int node_grid = (NN + 3) / 4;       // 12500

    // Layer 1: feat @ W1 -> ftb (bf16, MFMA) + el/er fused; agg -> hB (f32)
    k_mgemm<true><<<dim3(mg_grid), b256, 0, stream>>>(feat, wtg, al1, ar1, dflag, (bf16*)ftb, el, er);
    k_agg<128, true, false><<<dim3(node_grid), b256, 0, stream>>>(ftb, el, er, rowptr, csrsrc, b1, dflag, hB);

    // Layer 2: hB @ W2 -> ftb (bf16, MFMA) + el/er fused; agg -> hB
    k_mgemm<false><<<dim3(mg_grid), b256, 0, stream>>>(hB, wtg + 16384, al2, ar2, dflag, (bf16*)ftb, el, er);
    k_agg<128, true, false><<<dim3(node_grid), b256, 0, stream>>>(ftb, el, er, rowptr, csrsrc, b2, dflag, hB);

    // Layer 3 (all f32, vector): hB @ W3 -> ft3 + el/er fused; agg -> d_out
    k_gemm<false, 16, 1, false><<<dim3(gemm_grid), b256, 0, stream>>>(hB, W3, al3, ar3, dflag, ftb, el, er);
    k_agg<16, false, true><<<dim3(node_grid), b256, 0, stream>>>(ftb, el, er, rowptr, csrsrc, b3, dflag, d_out);
}